// Round 2
// baseline (698.999 us; speedup 1.0000x reference)
//
#include <hip/hip_runtime.h>

#define BB 256
#define TT 1024
#define II 3
#define HH 128
#define OO 3

#if __has_builtin(__builtin_amdgcn_exp2f)
#define EXP2F __builtin_amdgcn_exp2f
#else
#define EXP2F exp2f
#endif
#if __has_builtin(__builtin_amdgcn_rcpf)
#define RCPF __builtin_amdgcn_rcpf
#else
#define RCPF(x) (1.0f / (x))
#endif

// tanh(x) = 1 - 2/(e^{2x}+1); e^{2x} = 2^{x * 2*log2(e)}
__device__ __forceinline__ float fast_tanh(float x) {
    float e = EXP2F(x * 2.885390081777927f);
    return 1.0f - 2.0f * RCPF(e + 1.0f);
}

// One block per batch element. 128 threads = one hidden unit each.
// W_hh row in registers; h(t) broadcast from double-buffered LDS.
__global__ __launch_bounds__(128, 1) void rnn_kernel(
    const float* __restrict__ x,    // [B,T,I] fp32
    const float* __restrict__ Wih,  // [H,I]
    const float* __restrict__ Whh,  // [H,H]
    const float* __restrict__ bih,  // [H]
    const float* __restrict__ bhh,  // [H]
    const float* __restrict__ h0,   // [1,H]
    float* __restrict__ hid)        // [B,T,H] fp32 (output region 2)
{
    __shared__ float4 xs[TT];        // staged inputs: (x0,x1,x2,pad) per t
    __shared__ float hbuf[2][HH];    // double-buffered hidden state

    const int h = threadIdx.x;
    const int b = blockIdx.x;

    // --- W_hh row h into registers: 32x global_load_dwordx4 ---
    float w[HH];
    {
        const float4* wv = (const float4*)(Whh + h * HH);
#pragma unroll
        for (int j = 0; j < HH / 4; j++) {
            float4 v = wv[j];
            w[4 * j + 0] = v.x;
            w[4 * j + 1] = v.y;
            w[4 * j + 2] = v.z;
            w[4 * j + 3] = v.w;
        }
    }
    const float wi0 = Wih[h * II + 0];
    const float wi1 = Wih[h * II + 1];
    const float wi2 = Wih[h * II + 2];
    const float bias = bih[h] + bhh[h];

    hbuf[0][h] = h0[h];

    // --- stage this batch's inputs into LDS ---
    const float* xb = x + (size_t)b * TT * II;
    for (int idx = h; idx < TT * II; idx += HH) {
        int t = idx / 3;
        int c = idx - t * 3;
        ((float*)&xs[t])[c] = xb[idx];
    }
    __syncthreads();

    float* hb = hid + (size_t)b * TT * HH + h;

    for (int t = 0; t < TT; t++) {
        float4 xv = xs[t];  // LDS broadcast (same addr all lanes)
        float a0 = fmaf(xv.x, wi0, bias);
        a0 = fmaf(xv.y, wi1, a0);
        a0 = fmaf(xv.z, wi2, a0);
        float a1 = 0.f, a2 = 0.f, a3 = 0.f;

        const float4* hv = (const float4*)hbuf[t & 1];
#pragma unroll
        for (int j = 0; j < HH / 4; j++) {
            float4 hh = hv[j];  // ds_read_b128, broadcast
            a0 = fmaf(w[4 * j + 0], hh.x, a0);
            a1 = fmaf(w[4 * j + 1], hh.y, a1);
            a2 = fmaf(w[4 * j + 2], hh.z, a2);
            a3 = fmaf(w[4 * j + 3], hh.w, a3);
        }
        float acc = (a0 + a1) + (a2 + a3);
        float th = fast_tanh(acc);

        hbuf[(t + 1) & 1][h] = th;
        hb[t * HH] = th;
        __syncthreads();
    }
}

// Output projection: out[bt,o] = sum_h hid[bt,h] * W_out[o,h] + b_out[o]
__global__ void outproj_kernel(
    const float* __restrict__ hid,   // [B*T, H] fp32
    const float* __restrict__ Wout,  // [O,H]
    const float* __restrict__ bout,  // [O]
    float* __restrict__ out)         // [B*T, O] fp32
{
    __shared__ float wl[OO][HH];
    __shared__ float bl[OO];
    const int tid = threadIdx.x;

    for (int i = tid; i < OO * HH; i += 256)
        wl[i / HH][i & (HH - 1)] = Wout[i];
    if (tid < OO) bl[tid] = bout[tid];
    __syncthreads();

    const int bt = blockIdx.x * 256 + tid;
    const float4* hp = (const float4*)(hid + (size_t)bt * HH);

    float a0 = bl[0], a1 = bl[1], a2 = bl[2];
#pragma unroll
    for (int j = 0; j < HH / 4; j++) {
        float4 v = hp[j];
        float hf[4] = {v.x, v.y, v.z, v.w};
#pragma unroll
        for (int r = 0; r < 4; r++) {
            int k = j * 4 + r;
            a0 = fmaf(hf[r], wl[0][k], a0);
            a1 = fmaf(hf[r], wl[1][k], a1);
            a2 = fmaf(hf[r], wl[2][k], a2);
        }
    }
    float* op = out + (size_t)bt * OO;
    op[0] = a0;
    op[1] = a1;
    op[2] = a2;
}

extern "C" void kernel_launch(void* const* d_in, const int* in_sizes, int n_in,
                              void* d_out, int out_size, void* d_ws, size_t ws_size,
                              hipStream_t stream) {
    const float* x    = (const float*)d_in[0];  // [256,1024,3]
    const float* Wih  = (const float*)d_in[1];  // [128,3]
    const float* Whh  = (const float*)d_in[2];  // [128,128]
    const float* bih  = (const float*)d_in[3];  // [128]
    const float* bhh  = (const float*)d_in[4];  // [128]
    const float* h0   = (const float*)d_in[5];  // [1,128]
    const float* Wout = (const float*)d_in[6];  // [3,128]
    const float* bout = (const float*)d_in[7];  // [3]

    float* out = (float*)d_out;                 // [B,T,O] first
    float* hid = out + (size_t)BB * TT * OO;    // then [B,T,H]

    rnn_kernel<<<BB, HH, 0, stream>>>(x, Wih, Whh, bih, bhh, h0, hid);
    outproj_kernel<<<(BB * TT) / 256, 256, 0, stream>>>(hid, Wout, bout, out);
}

// Round 3
// 590.791 us; speedup vs baseline: 1.1832x; 1.1832x over previous
//
#include <hip/hip_runtime.h>

#define BB 256
#define TT 1024
#define II 3
#define HH 128
#define OO 3
#define NT 576   // 512 compute threads (8 waves) + 64-thread projection wave

#if __has_builtin(__builtin_amdgcn_exp2f)
#define EXP2F __builtin_amdgcn_exp2f
#else
#define EXP2F exp2f
#endif
#if __has_builtin(__builtin_amdgcn_rcpf)
#define RCPF __builtin_amdgcn_rcpf
#else
#define RCPF(x) (1.0f / (x))
#endif

// tanh(x) = 1 - 2/(e^{2x}+1)
__device__ __forceinline__ float fast_tanh(float x) {
    float e = EXP2F(x * 2.885390081777927f);
    return 1.0f - 2.0f * RCPF(e + 1.0f);
}

// One block per batch element.
// Threads [0,512): (q = tid>>7, h = tid&127) -> partial dot of W_hh[h][32q..32q+31]
//   with h(t)[32q..32q+31] (broadcast LDS reads), partials to pbuf, two-phase reduce.
// Threads [512,576): projection wave — computes out[b,t-1] = W_out @ h(t-1) + b_out
//   via shfl_xor butterfly while compute waves run phase A (hidden in barrier slack).
__global__ __launch_bounds__(NT) void rnn_kernel(
    const float* __restrict__ x,     // [B,T,I]
    const float* __restrict__ Wih,   // [H,I]
    const float* __restrict__ Whh,   // [H,H]
    const float* __restrict__ bih,   // [H]
    const float* __restrict__ bhh,   // [H]
    const float* __restrict__ h0,    // [1,H]
    const float* __restrict__ Wout,  // [O,H]
    const float* __restrict__ bout,  // [O]
    float* __restrict__ out,         // [B,T,O]
    float* __restrict__ hid)         // [B,T,H]
{
    __shared__ float4 xs[TT];        // (x0,x1,x2,pad) per t
    __shared__ float hbuf[2][HH];    // double-buffered hidden state
    __shared__ float pbuf[4][HH];    // per-q partial dots

    const int tid = threadIdx.x;
    const int b = blockIdx.x;

    // --- stage inputs; init h(0) ---
    const float* xb = x + (size_t)b * TT * II;
    for (int idx = tid; idx < TT * II; idx += NT) {
        int t = idx / 3;
        int c = idx - t * 3;
        ((float*)&xs[t])[c] = xb[idx];
    }
    if (tid < HH) hbuf[0][tid] = h0[tid];

    if (tid < 512) {
        // ================= compute waves =================
        const int h = tid & 127;
        const int q = tid >> 7;

        float w[32];
        {
            const float4* wv = (const float4*)(Whh + h * HH + 32 * q);
#pragma unroll
            for (int j = 0; j < 8; j++) {
                float4 v = wv[j];
                w[4 * j + 0] = v.x;
                w[4 * j + 1] = v.y;
                w[4 * j + 2] = v.z;
                w[4 * j + 3] = v.w;
            }
        }
        const float wi0 = Wih[h * II + 0];
        const float wi1 = Wih[h * II + 1];
        const float wi2 = Wih[h * II + 2];
        const float bias = bih[h] + bhh[h];

        float* hb = hid + (size_t)b * TT * HH + h;

        __syncthreads();

        for (int t = 0; t < TT; t++) {
            // phase A: partial dot over this thread's 32-element K-segment
            float a0, a1 = 0.f, a2 = 0.f, a3 = 0.f;
            if (q == 0) {
                float4 xv = xs[t];  // broadcast
                a0 = fmaf(xv.x, wi0, bias);
                a0 = fmaf(xv.y, wi1, a0);
                a0 = fmaf(xv.z, wi2, a0);
            } else {
                a0 = 0.f;
            }
            const float4* hv = (const float4*)(&hbuf[t & 1][32 * q]);  // wave-uniform addr
#pragma unroll
            for (int j = 0; j < 8; j++) {
                float4 hh = hv[j];  // ds_read_b128 broadcast
                a0 = fmaf(w[4 * j + 0], hh.x, a0);
                a1 = fmaf(w[4 * j + 1], hh.y, a1);
                a2 = fmaf(w[4 * j + 2], hh.z, a2);
                a3 = fmaf(w[4 * j + 3], hh.w, a3);
            }
            pbuf[q][h] = (a0 + a1) + (a2 + a3);  // conflict-free (consecutive h)
            __syncthreads();

            // phase B: waves 0-1 reduce + tanh + publish
            if (tid < HH) {
                float s = (pbuf[0][h] + pbuf[1][h]) + (pbuf[2][h] + pbuf[3][h]);
                float th = fast_tanh(s);
                hbuf[(t + 1) & 1][h] = th;
                hb[t * HH] = th;  // coalesced 512B store
            }
            __syncthreads();
        }
    } else {
        // ================= projection wave =================
        const int L = tid - 512;  // lane 0..63; owns h = 2L, 2L+1
        const float w00 = Wout[0 * HH + 2 * L], w01 = Wout[0 * HH + 2 * L + 1];
        const float w10 = Wout[1 * HH + 2 * L], w11 = Wout[1 * HH + 2 * L + 1];
        const float w20 = Wout[2 * HH + 2 * L], w21 = Wout[2 * HH + 2 * L + 1];
        const float b0 = bout[0], b1 = bout[1], b2 = bout[2];
        float* ob = out + (size_t)b * TT * OO;

        __syncthreads();  // matches compute pre-loop barrier

        for (int t = 0; t < TT; t++) {
            if (t > 0) {
                // h(t-1) lives in hbuf[t&1]; valid until compute phase B of step t+1
                const float* hc = hbuf[t & 1];
                float hv0 = hc[2 * L], hv1 = hc[2 * L + 1];
                float p0 = fmaf(hv0, w00, hv1 * w01);
                float p1 = fmaf(hv0, w10, hv1 * w11);
                float p2 = fmaf(hv0, w20, hv1 * w21);
#pragma unroll
                for (int m = 32; m >= 1; m >>= 1) {
                    p0 += __shfl_xor(p0, m);
                    p1 += __shfl_xor(p1, m);
                    p2 += __shfl_xor(p2, m);
                }
                if (L == 0) {
                    float* o = ob + (size_t)(t - 1) * OO;
                    o[0] = p0 + b0;
                    o[1] = p1 + b1;
                    o[2] = p2 + b2;
                }
            }
            __syncthreads();  // barrier 1
            __syncthreads();  // barrier 2
        }
        // final projection: h(1023) is in hbuf[1024 & 1] = hbuf[0]
        {
            const float* hc = hbuf[0];
            float hv0 = hc[2 * L], hv1 = hc[2 * L + 1];
            float p0 = fmaf(hv0, w00, hv1 * w01);
            float p1 = fmaf(hv0, w10, hv1 * w11);
            float p2 = fmaf(hv0, w20, hv1 * w21);
#pragma unroll
            for (int m = 32; m >= 1; m >>= 1) {
                p0 += __shfl_xor(p0, m);
                p1 += __shfl_xor(p1, m);
                p2 += __shfl_xor(p2, m);
            }
            if (L == 0) {
                float* o = ob + (size_t)(TT - 1) * OO;
                o[0] = p0 + b0;
                o[1] = p1 + b1;
                o[2] = p2 + b2;
            }
        }
    }
}

extern "C" void kernel_launch(void* const* d_in, const int* in_sizes, int n_in,
                              void* d_out, int out_size, void* d_ws, size_t ws_size,
                              hipStream_t stream) {
    const float* x    = (const float*)d_in[0];  // [256,1024,3]
    const float* Wih  = (const float*)d_in[1];  // [128,3]
    const float* Whh  = (const float*)d_in[2];  // [128,128]
    const float* bih  = (const float*)d_in[3];  // [128]
    const float* bhh  = (const float*)d_in[4];  // [128]
    const float* h0   = (const float*)d_in[5];  // [1,128]
    const float* Wout = (const float*)d_in[6];  // [3,128]
    const float* bout = (const float*)d_in[7];  // [3]

    float* out = (float*)d_out;                 // [B,T,O] first
    float* hid = out + (size_t)BB * TT * OO;    // then [B,T,H]

    rnn_kernel<<<BB, NT, 0, stream>>>(x, Wih, Whh, bih, bhh, h0, Wout, bout, out, hid);
}

// Round 4
// 546.087 us; speedup vs baseline: 1.2800x; 1.0819x over previous
//
#include <hip/hip_runtime.h>

#define BB 256
#define TT 1024
#define II 3
#define HH 128
#define OO 3
#define NT 576   // 512 compute threads (8 waves) + 64-thread projection/store wave

#if __has_builtin(__builtin_amdgcn_exp2f)
#define EXP2F __builtin_amdgcn_exp2f
#else
#define EXP2F exp2f
#endif
#if __has_builtin(__builtin_amdgcn_rcpf)
#define RCPF __builtin_amdgcn_rcpf
#else
#define RCPF(x) (1.0f / (x))
#endif

// tanh(x) = 1 - 2/(e^{2x}+1)
__device__ __forceinline__ float fast_tanh(float x) {
    float e = EXP2F(x * 2.885390081777927f);
    return 1.0f - 2.0f * RCPF(e + 1.0f);
}

// Workgroup barrier that fences LDS only — does NOT drain vmcnt, so global
// stores stay in flight across it (unlike __syncthreads, which emits
// s_waitcnt vmcnt(0) and puts store-ack latency on the critical path).
// All cross-wave dataflow in this kernel goes through LDS, so this is safe.
__device__ __forceinline__ void bar_lds() {
    asm volatile("s_waitcnt lgkmcnt(0)\n\ts_barrier" ::: "memory");
}

// One block per batch element. One s_barrier per timestep.
// Waves 0-7: wave w owns outputs h = 16w..16w+15; lane = sub*16 + o,
//   sub = lane>>4 selects a 32-wide K-segment; in-wave shfl_xor reduction.
// Wave 8: stores hid[b,t-1] (coalesced 512B) + out[b,t-1] each step.
__global__ __launch_bounds__(NT) void rnn_kernel(
    const float* __restrict__ x,     // [B,T,I]
    const float* __restrict__ Wih,   // [H,I]
    const float* __restrict__ Whh,   // [H,H]
    const float* __restrict__ bih,   // [H]
    const float* __restrict__ bhh,   // [H]
    const float* __restrict__ h0,    // [1,H]
    const float* __restrict__ Wout,  // [O,H]
    const float* __restrict__ bout,  // [O]
    float* __restrict__ out,         // [B,T,O]
    float* __restrict__ hid)         // [B,T,H]
{
    __shared__ __align__(16) float4 xs[TT];      // (x0,x1,x2,pad) per t
    __shared__ __align__(16) float hbuf[2][HH];  // double-buffered hidden state

    const int tid = threadIdx.x;
    const int b = blockIdx.x;

    // --- stage inputs; init h(0) ---
    const float* xb = x + (size_t)b * TT * II;
    for (int idx = tid; idx < TT * II; idx += NT) {
        int t = idx / 3;
        int c = idx - t * 3;
        ((float*)&xs[t])[c] = xb[idx];
    }
    if (tid < HH) hbuf[0][tid] = h0[tid];

    if (tid < 512) {
        // ================= compute waves =================
        const int lane = tid & 63;
        const int wv   = tid >> 6;        // wave 0..7
        const int o16  = lane & 15;       // output within wave's 16
        const int sub  = lane >> 4;       // K-segment 0..3
        const int h    = wv * 16 + o16;   // global output index

        // W_hh[h][32*sub .. 32*sub+31] into registers
        float w[32];
        {
            const float4* wp = (const float4*)(Whh + h * HH + 32 * sub);
#pragma unroll
            for (int j = 0; j < 8; j++) {
                float4 v = wp[j];
                w[4 * j + 0] = v.x;
                w[4 * j + 1] = v.y;
                w[4 * j + 2] = v.z;
                w[4 * j + 3] = v.w;
            }
        }
        const float wi0 = Wih[h * II + 0];
        const float wi1 = Wih[h * II + 1];
        const float wi2 = Wih[h * II + 2];
        const float bias = bih[h] + bhh[h];

        bar_lds();

        for (int t = 0; t < TT; t++) {
            const float* hcur = hbuf[t & 1];
            float* hnext = hbuf[(t + 1) & 1];

            float a0 = 0.f, a1 = 0.f, a2 = 0.f, a3 = 0.f;
            if (sub == 0) {
                float4 xv = xs[t];  // broadcast
                a0 = fmaf(xv.x, wi0, bias);
                a0 = fmaf(xv.y, wi1, a0);
                a0 = fmaf(xv.z, wi2, a0);
            }
            const float4* hv = (const float4*)(hcur + 32 * sub);
#pragma unroll
            for (int j = 0; j < 8; j++) {
                float4 hh = hv[j];  // 4 distinct addrs/wave, 16-lane broadcast each
                a0 = fmaf(w[4 * j + 0], hh.x, a0);
                a1 = fmaf(w[4 * j + 1], hh.y, a1);
                a2 = fmaf(w[4 * j + 2], hh.z, a2);
                a3 = fmaf(w[4 * j + 3], hh.w, a3);
            }
            float s = (a0 + a1) + (a2 + a3);
            s += __shfl_xor(s, 16);   // reduce across sub
            s += __shfl_xor(s, 32);
            float th = fast_tanh(s);
            if (sub == 0) hnext[h] = th;
            bar_lds();
        }
    } else {
        // ================= projection + store wave =================
        const int L = tid - 512;  // lane 0..63; owns h = 2L, 2L+1
        const float w00 = Wout[0 * HH + 2 * L], w01 = Wout[0 * HH + 2 * L + 1];
        const float w10 = Wout[1 * HH + 2 * L], w11 = Wout[1 * HH + 2 * L + 1];
        const float w20 = Wout[2 * HH + 2 * L], w21 = Wout[2 * HH + 2 * L + 1];
        const float b0 = bout[0], b1 = bout[1], b2 = bout[2];
        float* ob = out + (size_t)b * TT * OO;
        float* hb = hid + (size_t)b * TT * HH;

        bar_lds();

        for (int t = 0; t < TT; t++) {
            if (t > 0) {
                // hbuf[t&1] = hiddens[t-1], stable during step t
                const float2 hv = ((const float2*)hbuf[t & 1])[L];
                ((float2*)(hb + (size_t)(t - 1) * HH))[L] = hv;  // coalesced 512B
                float p0 = fmaf(hv.x, w00, hv.y * w01);
                float p1 = fmaf(hv.x, w10, hv.y * w11);
                float p2 = fmaf(hv.x, w20, hv.y * w21);
#pragma unroll
                for (int m = 32; m >= 1; m >>= 1) {
                    p0 += __shfl_xor(p0, m);
                    p1 += __shfl_xor(p1, m);
                    p2 += __shfl_xor(p2, m);
                }
                if (L == 0) {
                    float* o = ob + (size_t)(t - 1) * OO;
                    o[0] = p0 + b0;
                    o[1] = p1 + b1;
                    o[2] = p2 + b2;
                }
            }
            bar_lds();
        }
        // tail: hiddens[1023] = hbuf[1024 & 1] = hbuf[0] (compute waves done)
        {
            const float2 hv = ((const float2*)hbuf[0])[L];
            ((float2*)(hb + (size_t)(TT - 1) * HH))[L] = hv;
            float p0 = fmaf(hv.x, w00, hv.y * w01);
            float p1 = fmaf(hv.x, w10, hv.y * w11);
            float p2 = fmaf(hv.x, w20, hv.y * w21);
#pragma unroll
            for (int m = 32; m >= 1; m >>= 1) {
                p0 += __shfl_xor(p0, m);
                p1 += __shfl_xor(p1, m);
                p2 += __shfl_xor(p2, m);
            }
            if (L == 0) {
                float* o = ob + (size_t)(TT - 1) * OO;
                o[0] = p0 + b0;
                o[1] = p1 + b1;
                o[2] = p2 + b2;
            }
        }
    }
}

extern "C" void kernel_launch(void* const* d_in, const int* in_sizes, int n_in,
                              void* d_out, int out_size, void* d_ws, size_t ws_size,
                              hipStream_t stream) {
    const float* x    = (const float*)d_in[0];  // [256,1024,3]
    const float* Wih  = (const float*)d_in[1];  // [128,3]
    const float* Whh  = (const float*)d_in[2];  // [128,128]
    const float* bih  = (const float*)d_in[3];  // [128]
    const float* bhh  = (const float*)d_in[4];  // [128]
    const float* h0   = (const float*)d_in[5];  // [1,128]
    const float* Wout = (const float*)d_in[6];  // [3,128]
    const float* bout = (const float*)d_in[7];  // [3]

    float* out = (float*)d_out;                 // [B,T,O] first
    float* hid = out + (size_t)BB * TT * OO;    // then [B,T,H]

    rnn_kernel<<<BB, NT, 0, stream>>>(x, Wih, Whh, bih, bhh, h0, Wout, bout, out, hid);
}